// Round 2
// baseline (2802.800 us; speedup 1.0000x reference)
//
#include <hip/hip_runtime.h>

typedef unsigned short u16;
typedef unsigned int   u32;
typedef __attribute__((ext_vector_type(8))) short bf16x8;
typedef __attribute__((ext_vector_type(4))) float f32x4;

#define GK 768            // K dim of all GEMMs
#define NSTEP 196
#define NWG 96            // recurrence workgroups
#define CPW 8             // channels per recurrence wg (96*8 = 768)
#define RROWS 24          // 3 gates * CPW

__device__ __forceinline__ u16 f2bf(float f) {
    u32 u = __float_as_uint(f);
    u = (u + 0x7fffu + ((u >> 16) & 1u)) >> 16;
    return (u16)u;
}
__device__ __forceinline__ float bf2f(u16 h) { return __uint_as_float(((u32)h) << 16); }

// ---------------------------------------------------------------------------
// fp32 -> bf16 convert for x, Wx, Wp
// ---------------------------------------------------------------------------
__global__ __launch_bounds__(256) void cvt_kernel(
    const float4* __restrict__ x, const float4* __restrict__ wx,
    const float4* __restrict__ wp,
    u32* __restrict__ xb, u32* __restrict__ wxb, u32* __restrict__ wpb)
{
    const int N1 = 9633792 / 4, N2 = 1769472 / 4;
    int i = blockIdx.x * 256 + threadIdx.x;
    const float4* src; u32* dst; int off;
    if (i < N1)            { src = x;  dst = xb;  off = i; }
    else if (i < N1 + N2)  { src = wx; dst = wxb; off = i - N1; }
    else                   { src = wp; dst = wpb; off = i - N1 - N2; }
    float4 v = src[off];
    u32 lo = (u32)f2bf(v.x) | ((u32)f2bf(v.y) << 16);
    u32 hi = (u32)f2bf(v.z) | ((u32)f2bf(v.w) << 16);
    dst[(size_t)off * 2]     = lo;
    dst[(size_t)off * 2 + 1] = hi;
}

// ---------------------------------------------------------------------------
// GEMM: out[M][N] = A[M][K] @ B[N][K]^T   (A,B bf16 row-major K-contiguous)
// MODE 1: += bias[col], bf16 out remapped to [n][b][col] with m = b*196+n
// MODE 0: fp32 out at [m][col], no bias
// ---------------------------------------------------------------------------
template<int MODE>
__global__ __launch_bounds__(256) void gemm_bt(
    const u16* __restrict__ A, const u16* __restrict__ B,
    const float* __restrict__ bias, void* __restrict__ outv)
{
    __shared__ u16 As[128 * 40];
    __shared__ u16 Bs[128 * 40];
    const int tid  = threadIdx.x;
    const int lane = tid & 63;
    const int wv   = tid >> 6;
    const int m0 = blockIdx.y * 128;
    const int n0 = blockIdx.x * 128;
    const int wm = (wv & 1) * 64;
    const int wn = (wv >> 1) * 64;

    f32x4 acc[4][4];
#pragma unroll
    for (int i = 0; i < 4; ++i)
#pragma unroll
        for (int j = 0; j < 4; ++j) acc[i][j] = (f32x4){0.f, 0.f, 0.f, 0.f};

    const int r0 = tid >> 2, q0 = tid & 3;
    const u16* gA0 = A + (size_t)(m0 + r0)      * GK + q0 * 8;
    const u16* gA1 = A + (size_t)(m0 + r0 + 64) * GK + q0 * 8;
    const u16* gB0 = B + (size_t)(n0 + r0)      * GK + q0 * 8;
    const u16* gB1 = B + (size_t)(n0 + r0 + 64) * GK + q0 * 8;
    u16* sA0 = As + r0 * 40 + q0 * 8;
    u16* sA1 = As + (r0 + 64) * 40 + q0 * 8;
    u16* sB0 = Bs + r0 * 40 + q0 * 8;
    u16* sB1 = Bs + (r0 + 64) * 40 + q0 * 8;

    const int fr = lane & 15, fq = lane >> 4;
    const u16* fA = As + (wm + fr) * 40 + fq * 8;
    const u16* fB = Bs + (wn + fr) * 40 + fq * 8;

    for (int kt = 0; kt < GK / 32; ++kt) {
        uint4 a0 = *(const uint4*)(gA0 + kt * 32);
        uint4 a1 = *(const uint4*)(gA1 + kt * 32);
        uint4 b0 = *(const uint4*)(gB0 + kt * 32);
        uint4 b1 = *(const uint4*)(gB1 + kt * 32);
        __syncthreads();
        *(uint4*)sA0 = a0; *(uint4*)sA1 = a1;
        *(uint4*)sB0 = b0; *(uint4*)sB1 = b1;
        __syncthreads();
        bf16x8 af[4], bfr[4];
#pragma unroll
        for (int mi = 0; mi < 4; ++mi) af[mi]  = *(const bf16x8*)(fA + mi * 16 * 40);
#pragma unroll
        for (int ni = 0; ni < 4; ++ni) bfr[ni] = *(const bf16x8*)(fB + ni * 16 * 40);
#pragma unroll
        for (int mi = 0; mi < 4; ++mi)
#pragma unroll
            for (int ni = 0; ni < 4; ++ni)
                acc[mi][ni] = __builtin_amdgcn_mfma_f32_16x16x32_bf16(
                    af[mi], bfr[ni], acc[mi][ni], 0, 0, 0);
    }

    if (MODE == 1) {
        u16* out = (u16*)outv;
#pragma unroll
        for (int mi = 0; mi < 4; ++mi) {
#pragma unroll
            for (int ni = 0; ni < 4; ++ni) {
                int col = n0 + wn + ni * 16 + fr;
                float bv = bias[col];
#pragma unroll
                for (int r = 0; r < 4; ++r) {
                    int m = m0 + wm + mi * 16 + fq * 4 + r;
                    int b = m / 196;
                    int nn = m - b * 196;
                    u16 hv = f2bf(acc[mi][ni][r] + bv);
                    int other = __shfl_xor((int)hv, 1, 64);
                    if (!(lane & 1)) {
                        u32 packed = (u32)hv | (((u32)(u16)other) << 16);
                        size_t eidx = ((size_t)nn * 64 + (size_t)b) * 2304 + (size_t)col;
                        *((u32*)out + (eidx >> 1)) = packed;
                    }
                }
            }
        }
    } else {
        float* out = (float*)outv;
#pragma unroll
        for (int mi = 0; mi < 4; ++mi) {
#pragma unroll
            for (int ni = 0; ni < 4; ++ni) {
                int col = n0 + wn + ni * 16 + fr;
#pragma unroll
                for (int r = 0; r < 4; ++r) {
                    int m = m0 + wm + mi * 16 + fq * 4 + r;
                    out[(size_t)m * 768 + col] = acc[mi][ni][r];
                }
            }
        }
    }
}

// ---------------------------------------------------------------------------
// Persistent cooperative GRU recurrence, fence-free.
// 96 wgs x 512 threads (8 waves = 4 batch-tiles x 2 K-halves).
// Wh slice (24 rows) lives in REGISTERS as MFMA B-frags (96 VGPR/lane).
// h exchanged via L3: sc1 atomic stores / sc1 atomic loads, relaxed flags.
// NO acquire fences, NO release fences -> no buffer_inv / wbl2 per step.
// ---------------------------------------------------------------------------
__global__ __launch_bounds__(512) void recur_kernel(
    const u16* __restrict__ xz,   // [196][64][2304] bf16 (x proj + bx)
    const float* __restrict__ Wh, // [2304][768] f32
    const float* __restrict__ bh, // [2304] f32
    u16* __restrict__ hs,         // [64][196][768] bf16 out
    u16* hb,                      // 2 x [64][768] bf16 ping-pong
    int* flags)                   // [NWG]
{
    __shared__ float hz_s[2][64 * 28];   // partial h_zrn per K-half, [b][24 pad 28]
    __shared__ float hold_s[512];        // previous h for own channels [b][8]

    const int tid  = threadIdx.x;
    const int wg   = blockIdx.x;
    const int c0   = wg * CPW;
    const int lane = tid & 63;
    const int wv   = tid >> 6;
    const int mi   = wv & 3;     // batch tile (16 batches)
    const int kh   = wv >> 2;    // K half (384 each)
    const int fr   = lane & 15, fq = lane >> 4;
    u32* hbu = (u32*)hb;

    // ---- one-time: Wh slice -> B-frags in registers (bf16), rows>=24 zero ----
    bf16x8 bfrag[2][12];
#pragma unroll
    for (int ni = 0; ni < 2; ++ni) {
        int row = ni * 16 + fr;
        bool valid = row < RROWS;
        int gate = row >> 3, ch = row & 7;
        const float* wp = Wh + (size_t)(valid ? (gate * 768 + c0 + ch) : 0) * 768;
#pragma unroll
        for (int kk = 0; kk < 12; ++kk) {
            int k0 = (kh * 12 + kk) * 32 + fq * 8;
            float4 f0 = *(const float4*)(wp + k0);
            float4 f1 = *(const float4*)(wp + k0 + 4);
            bf16x8 b;
            b[0] = (short)f2bf(f0.x); b[1] = (short)f2bf(f0.y);
            b[2] = (short)f2bf(f0.z); b[3] = (short)f2bf(f0.w);
            b[4] = (short)f2bf(f1.x); b[5] = (short)f2bf(f1.y);
            b[6] = (short)f2bf(f1.z); b[7] = (short)f2bf(f1.w);
            if (!valid) b = (bf16x8){0,0,0,0,0,0,0,0};
            bfrag[ni][kk] = b;
        }
    }

    // ---- one-time: zero h_{-1} (read buffer 1) slice + hold_s ----
    hold_s[tid] = 0.f;
    if (tid < 256) {
        int b = tid >> 2, j = tid & 3;
        __hip_atomic_store(hbu + ((49152 + b * 768 + c0 + 2 * j) >> 1), 0u,
                           __ATOMIC_RELAXED, __HIP_MEMORY_SCOPE_AGENT);
    }
    __syncthreads();   // drains vmcnt for all waves
    if (tid == 0)
        __hip_atomic_store(&flags[wg], 1, __ATOMIC_RELAXED, __HIP_MEMORY_SCOPE_AGENT);

    // gate-phase constants (one (batch,channel) per thread)
    const int gb = tid >> 3, gi = tid & 7;
    const int gc = c0 + gi;
    const float bh0 = bh[gc], bh1 = bh[768 + gc], bh2 = bh[1536 + gc];

    // A-fragment base (u32 units): batch row = mi*16+fr, k = kh*384 + fq*8
    const int abase = (mi * 16 + fr) * 384 + kh * 192 + fq * 4;

    for (int n = 0; n < NSTEP; ++n) {
        // prefetch x-projection for this step (independent of h)
        size_t xoff = (size_t)n * 147456 + (size_t)gb * 2304 + (size_t)gc;
        float xg0 = bf2f(xz[xoff]);
        float xg1 = bf2f(xz[xoff + 768]);
        float xg2 = bf2f(xz[xoff + 1536]);

        // wait for all wgs to have published step n-1
        if (tid < 64) {
            const int target = n + 1;
            for (;;) {
                int v0 = __hip_atomic_load(&flags[lane], __ATOMIC_RELAXED,
                                           __HIP_MEMORY_SCOPE_AGENT);
                int v1 = __hip_atomic_load(&flags[lane + 32], __ATOMIC_RELAXED,
                                           __HIP_MEMORY_SCOPE_AGENT);
                int v = v0 < v1 ? v0 : v1;
                if (__all(v >= target)) break;
                __builtin_amdgcn_s_sleep(1);
            }
        }
        __syncthreads();

        const u32* hrd = (const u32*)(hb + ((n + 1) & 1) * 49152);

        // h_zrn partial GEMM: 16 batches x 24 rows, K-half via sc1 loads
        f32x4 acc0 = (f32x4){0.f, 0.f, 0.f, 0.f};
        f32x4 acc1 = (f32x4){0.f, 0.f, 0.f, 0.f};
#pragma unroll
        for (int kk = 0; kk < 12; ++kk) {
            union { u32 u[4]; bf16x8 v; } au;
            au.u[0] = __hip_atomic_load(hrd + abase + kk * 16 + 0, __ATOMIC_RELAXED, __HIP_MEMORY_SCOPE_AGENT);
            au.u[1] = __hip_atomic_load(hrd + abase + kk * 16 + 1, __ATOMIC_RELAXED, __HIP_MEMORY_SCOPE_AGENT);
            au.u[2] = __hip_atomic_load(hrd + abase + kk * 16 + 2, __ATOMIC_RELAXED, __HIP_MEMORY_SCOPE_AGENT);
            au.u[3] = __hip_atomic_load(hrd + abase + kk * 16 + 3, __ATOMIC_RELAXED, __HIP_MEMORY_SCOPE_AGENT);
            acc0 = __builtin_amdgcn_mfma_f32_16x16x32_bf16(au.v, bfrag[0][kk], acc0, 0, 0, 0);
            acc1 = __builtin_amdgcn_mfma_f32_16x16x32_bf16(au.v, bfrag[1][kk], acc1, 0, 0, 0);
        }
        {
            int bat = mi * 16 + fq * 4;
#pragma unroll
            for (int r = 0; r < 4; ++r)
                hz_s[kh][(bat + r) * 28 + fr] = acc0[r];
            if (fr < 8) {
#pragma unroll
                for (int r = 0; r < 4; ++r)
                    hz_s[kh][(bat + r) * 28 + 16 + fr] = acc1[r];
            }
        }
        __syncthreads();

        // gates: one (batch, channel) per thread
        float h0 = hz_s[0][gb * 28 + gi]      + hz_s[1][gb * 28 + gi]      + bh0;
        float h1 = hz_s[0][gb * 28 + 8 + gi]  + hz_s[1][gb * 28 + 8 + gi]  + bh1;
        float h2 = hz_s[0][gb * 28 + 16 + gi] + hz_s[1][gb * 28 + 16 + gi] + bh2;
        float z  = 1.f / (1.f + __expf(-(xg0 + h0)));
        float rr = 1.f / (1.f + __expf(-(xg1 + h1)));
        float pre = xg2 + rr * h2;
        float e2 = __expf(-2.f * pre);
        float nc = (1.f - e2) / (1.f + e2);
        float hold = hold_s[tid];
        float hnew = (1.f - z) * nc + z * hold;
        hold_s[tid] = hnew;
        u16 hv = f2bf(hnew);
        int other = __shfl_xor((int)hv, 1, 64);
        if (!(tid & 1)) {
            u32 packed = (u32)hv | (((u32)(u16)other) << 16);
            __hip_atomic_store(hbu + (((n & 1) * 49152 + gb * 768 + gc) >> 1), packed,
                               __ATOMIC_RELAXED, __HIP_MEMORY_SCOPE_AGENT);
            *((u32*)hs + (((size_t)(gb * 196 + n) * 768 + gc) >> 1)) = packed;
        }
        __syncthreads();   // all waves drain vmcnt before flag publish
        if (tid == 0)
            __hip_atomic_store(&flags[wg], n + 2, __ATOMIC_RELAXED, __HIP_MEMORY_SCOPE_AGENT);
    }
}

// ---------------------------------------------------------------------------
extern "C" void kernel_launch(void* const* d_in, const int* in_sizes, int n_in,
                              void* d_out, int out_size, void* d_ws, size_t ws_size,
                              hipStream_t stream)
{
    const float* x  = (const float*)d_in[0];
    const float* Wx = (const float*)d_in[1];
    const float* bx = (const float*)d_in[2];
    const float* Wh = (const float*)d_in[3];
    const float* bh = (const float*)d_in[4];
    const float* Wp = (const float*)d_in[5];
    float* out = (float*)d_out;

    char* ws = (char*)d_ws;
    size_t off = 0;
    auto wsalloc = [&](size_t bytes) -> void* {
        void* p = ws + off;
        off += (bytes + 255) & ~(size_t)255;
        return p;
    };
    u16* xb   = (u16*)wsalloc(9633792ull * 2);            // x bf16 [12544][768]
    u16* wxb  = (u16*)wsalloc(1769472ull * 2);            // Wx bf16 [2304][768]
    u16* wpb  = (u16*)wsalloc(589824ull * 2);             // Wp bf16 [768][768]
    u16* xzrn = (u16*)wsalloc(196ull * 64 * 2304 * 2);    // [n][b][3C] bf16
    u16* hs   = (u16*)wsalloc(12544ull * 768 * 2);        // [b][n][C] bf16
    u16* hb   = (u16*)wsalloc(2ull * 64 * 768 * 2);       // h ping-pong
    int* flags = (int*)wsalloc(1024);

    // 1) converts
    cvt_kernel<<<11712, 256, 0, stream>>>(
        (const float4*)x, (const float4*)Wx, (const float4*)Wp,
        (u32*)xb, (u32*)wxb, (u32*)wpb);

    // 2) x_zrn = seq @ Wx^T + bx  ->  [n][b][3C] bf16
    gemm_bt<1><<<dim3(18, 98), 256, 0, stream>>>(xb, wxb, bx, (void*)xzrn);

    // 3) cooperative recurrence
    {
        const u16* a0 = xzrn; const float* a1 = Wh; const float* a2 = bh;
        u16* a3 = hs; u16* a4 = hb; int* a5 = flags;
        void* args[6] = { &a0, &a1, &a2, &a3, &a4, &a5 };
        hipLaunchCooperativeKernel((void*)recur_kernel, dim3(NWG), dim3(512),
                                   args, 0, stream);
    }

    // 4) y = hs @ Wp^T -> d_out fp32
    gemm_bt<0><<<dim3(6, 98), 256, 0, stream>>>(hs, wpb, nullptr, (void*)out);
}

// Round 3
// 1487.296 us; speedup vs baseline: 1.8845x; 1.8845x over previous
//
#include <hip/hip_runtime.h>

typedef unsigned short u16;
typedef unsigned int   u32;
typedef __attribute__((ext_vector_type(8))) short bf16x8;
typedef __attribute__((ext_vector_type(4))) float f32x4;

#define GK 768            // K dim of all GEMMs
#define NSTEP 196
#define NWG 96            // recurrence workgroups
#define CPW 8             // channels per recurrence wg (96*8 = 768)
#define RROWS 24          // 3 gates * CPW
#define HSTEP 49152       // 64*768 elements per step slab

__device__ __forceinline__ u16 f2bf(float f) {
    u32 u = __float_as_uint(f);
    u = (u + 0x7fffu + ((u >> 16) & 1u)) >> 16;
    return (u16)u;
}
__device__ __forceinline__ float bf2f(u16 h) { return __uint_as_float(((u32)h) << 16); }

// ---------------------------------------------------------------------------
// fp32 -> bf16 convert for x, Wx, Wp; block 0 also zeros the barrier counters
// ---------------------------------------------------------------------------
__global__ __launch_bounds__(256) void cvt_kernel(
    const float4* __restrict__ x, const float4* __restrict__ wx,
    const float4* __restrict__ wp,
    u32* __restrict__ xb, u32* __restrict__ wxb, u32* __restrict__ wpb,
    int* __restrict__ cnt)
{
    const int N1 = 9633792 / 4, N2 = 1769472 / 4;
    int i = blockIdx.x * 256 + threadIdx.x;
    if (blockIdx.x == 0) cnt[threadIdx.x] = 0;   // 256 >= NSTEP
    const float4* src; u32* dst; int off;
    if (i < N1)            { src = x;  dst = xb;  off = i; }
    else if (i < N1 + N2)  { src = wx; dst = wxb; off = i - N1; }
    else                   { src = wp; dst = wpb; off = i - N1 - N2; }
    float4 v = src[off];
    u32 lo = (u32)f2bf(v.x) | ((u32)f2bf(v.y) << 16);
    u32 hi = (u32)f2bf(v.z) | ((u32)f2bf(v.w) << 16);
    dst[(size_t)off * 2]     = lo;
    dst[(size_t)off * 2 + 1] = hi;
}

// ---------------------------------------------------------------------------
// GEMM: out[M][N] = A[M][K] @ B[N][K]^T   (A,B bf16 row-major K-contiguous)
// MODE 1: += bias[col], bf16 out remapped to [n][b][col] with m = b*196+n
// MODE 0: fp32 out; A rows are m = n*64+b, output row remapped to b*196+n
// ---------------------------------------------------------------------------
template<int MODE>
__global__ __launch_bounds__(256) void gemm_bt(
    const u16* __restrict__ A, const u16* __restrict__ B,
    const float* __restrict__ bias, void* __restrict__ outv)
{
    __shared__ u16 As[128 * 40];
    __shared__ u16 Bs[128 * 40];
    const int tid  = threadIdx.x;
    const int lane = tid & 63;
    const int wv   = tid >> 6;
    const int m0 = blockIdx.y * 128;
    const int n0 = blockIdx.x * 128;
    const int wm = (wv & 1) * 64;
    const int wn = (wv >> 1) * 64;

    f32x4 acc[4][4];
#pragma unroll
    for (int i = 0; i < 4; ++i)
#pragma unroll
        for (int j = 0; j < 4; ++j) acc[i][j] = (f32x4){0.f, 0.f, 0.f, 0.f};

    const int r0 = tid >> 2, q0 = tid & 3;
    const u16* gA0 = A + (size_t)(m0 + r0)      * GK + q0 * 8;
    const u16* gA1 = A + (size_t)(m0 + r0 + 64) * GK + q0 * 8;
    const u16* gB0 = B + (size_t)(n0 + r0)      * GK + q0 * 8;
    const u16* gB1 = B + (size_t)(n0 + r0 + 64) * GK + q0 * 8;
    u16* sA0 = As + r0 * 40 + q0 * 8;
    u16* sA1 = As + (r0 + 64) * 40 + q0 * 8;
    u16* sB0 = Bs + r0 * 40 + q0 * 8;
    u16* sB1 = Bs + (r0 + 64) * 40 + q0 * 8;

    const int fr = lane & 15, fq = lane >> 4;
    const u16* fA = As + (wm + fr) * 40 + fq * 8;
    const u16* fB = Bs + (wn + fr) * 40 + fq * 8;

    for (int kt = 0; kt < GK / 32; ++kt) {
        uint4 a0 = *(const uint4*)(gA0 + kt * 32);
        uint4 a1 = *(const uint4*)(gA1 + kt * 32);
        uint4 b0 = *(const uint4*)(gB0 + kt * 32);
        uint4 b1 = *(const uint4*)(gB1 + kt * 32);
        __syncthreads();
        *(uint4*)sA0 = a0; *(uint4*)sA1 = a1;
        *(uint4*)sB0 = b0; *(uint4*)sB1 = b1;
        __syncthreads();
        bf16x8 af[4], bfr[4];
#pragma unroll
        for (int mi = 0; mi < 4; ++mi) af[mi]  = *(const bf16x8*)(fA + mi * 16 * 40);
#pragma unroll
        for (int ni = 0; ni < 4; ++ni) bfr[ni] = *(const bf16x8*)(fB + ni * 16 * 40);
#pragma unroll
        for (int mi = 0; mi < 4; ++mi)
#pragma unroll
            for (int ni = 0; ni < 4; ++ni)
                acc[mi][ni] = __builtin_amdgcn_mfma_f32_16x16x32_bf16(
                    af[mi], bfr[ni], acc[mi][ni], 0, 0, 0);
    }

    if (MODE == 1) {
        u16* out = (u16*)outv;
#pragma unroll
        for (int mi = 0; mi < 4; ++mi) {
#pragma unroll
            for (int ni = 0; ni < 4; ++ni) {
                int col = n0 + wn + ni * 16 + fr;
                float bv = bias[col];
#pragma unroll
                for (int r = 0; r < 4; ++r) {
                    int m = m0 + wm + mi * 16 + fq * 4 + r;
                    int b = m / 196;
                    int nn = m - b * 196;
                    u16 hv = f2bf(acc[mi][ni][r] + bv);
                    int other = __shfl_xor((int)hv, 1, 64);
                    if (!(lane & 1)) {
                        u32 packed = (u32)hv | (((u32)(u16)other) << 16);
                        size_t eidx = ((size_t)nn * 64 + (size_t)b) * 2304 + (size_t)col;
                        *((u32*)out + (eidx >> 1)) = packed;
                    }
                }
            }
        }
    } else {
        float* out = (float*)outv;
#pragma unroll
        for (int mi = 0; mi < 4; ++mi) {
#pragma unroll
            for (int ni = 0; ni < 4; ++ni) {
                int col = n0 + wn + ni * 16 + fr;
#pragma unroll
                for (int r = 0; r < 4; ++r) {
                    int m = m0 + wm + mi * 16 + fq * 4 + r;   // m = n*64 + b
                    int b = m & 63;
                    int nn = m >> 6;
                    out[((size_t)b * 196 + nn) * 768 + col] = acc[mi][ni][r];
                }
            }
        }
    }
}

// ---------------------------------------------------------------------------
// Persistent cooperative GRU recurrence.
// 96 wgs x 512 threads (8 waves = 4 batch-tiles x 2 K-halves).
// Wh slice (24 rows) lives in REGISTERS as MFMA B-frags.
// h exchange: per-step ROTATING buffer hsx[n][64][768]; producers publish
// with write-through agent atomic u32 stores; readers use NORMAL cached
// dwordx4 loads (addresses are fresh every step -> no stale-cache hazard).
// Barrier: one atomicAdd arrival per wg into cnt[n]; tid 0 polls cnt[n-1].
// ---------------------------------------------------------------------------
__global__ __launch_bounds__(512) void recur_kernel(
    const u16* __restrict__ xz,   // [196][64][2304] bf16 (x proj + bx)
    const float* __restrict__ Wh, // [2304][768] f32
    const float* __restrict__ bh, // [2304] f32
    u16* __restrict__ hsx,        // [196][64][768] bf16 (exchange + output)
    int* cnt)                     // [196] arrival counters (pre-zeroed)
{
    __shared__ float hz_s[2][64 * 28];   // partial h_zrn per K-half, [b][24 pad 28]
    __shared__ float hold_s[512];        // previous h for own channels [b][8]

    const int tid  = threadIdx.x;
    const int wg   = blockIdx.x;
    const int c0   = wg * CPW;
    const int lane = tid & 63;
    const int wv   = tid >> 6;
    const int mi   = wv & 3;     // batch tile (16 batches)
    const int kh   = wv >> 2;    // K half (384 each)
    const int fr   = lane & 15, fq = lane >> 4;

    // one-time: invalidate any stale (poison-era) L1/L2 lines
    __builtin_amdgcn_fence(__ATOMIC_ACQUIRE, "agent");

    // ---- one-time: Wh slice -> B-frags in registers (bf16), rows>=24 zero ----
    bf16x8 bfrag[2][12];
#pragma unroll
    for (int ni = 0; ni < 2; ++ni) {
        int row = ni * 16 + fr;
        bool valid = row < RROWS;
        int gate = row >> 3, ch = row & 7;
        const float* wp = Wh + (size_t)(valid ? (gate * 768 + c0 + ch) : 0) * 768;
#pragma unroll
        for (int kk = 0; kk < 12; ++kk) {
            int k0 = (kh * 12 + kk) * 32 + fq * 8;
            float4 f0 = *(const float4*)(wp + k0);
            float4 f1 = *(const float4*)(wp + k0 + 4);
            bf16x8 b;
            b[0] = (short)f2bf(f0.x); b[1] = (short)f2bf(f0.y);
            b[2] = (short)f2bf(f0.z); b[3] = (short)f2bf(f0.w);
            b[4] = (short)f2bf(f1.x); b[5] = (short)f2bf(f1.y);
            b[6] = (short)f2bf(f1.z); b[7] = (short)f2bf(f1.w);
            if (!valid) b = (bf16x8){0,0,0,0,0,0,0,0};
            bfrag[ni][kk] = b;
        }
    }

    hold_s[tid] = 0.f;
    __syncthreads();

    // gate-phase constants (one (batch,channel) per thread)
    const int gb = tid >> 3, gi = tid & 7;
    const int gc = c0 + gi;
    const float bh0 = bh[gc], bh1 = bh[768 + gc], bh2 = bh[1536 + gc];

    // A-fragment element offset within one step slab
    const int aoff = (mi * 16 + fr) * 768 + kh * 384 + fq * 8;

    for (int n = 0; n < NSTEP; ++n) {
        // prefetch x-projection for this step (independent of h)
        size_t xoff = (size_t)n * 147456 + (size_t)gb * 2304 + (size_t)gc;
        float xg0 = bf2f(xz[xoff]);
        float xg1 = bf2f(xz[xoff + 768]);
        float xg2 = bf2f(xz[xoff + 1536]);

        f32x4 acc0 = (f32x4){0.f, 0.f, 0.f, 0.f};
        f32x4 acc1 = (f32x4){0.f, 0.f, 0.f, 0.f};

        if (n > 0) {
            // wait for all wgs to have published step n-1
            if (tid == 0) {
                while (__hip_atomic_load(&cnt[n - 1], __ATOMIC_RELAXED,
                                         __HIP_MEMORY_SCOPE_AGENT) < NWG) {}
            }
            __syncthreads();

            const u16* ap = hsx + (size_t)(n - 1) * HSTEP + aoff;
#pragma unroll
            for (int kk = 0; kk < 12; ++kk) {
                bf16x8 a = *(const bf16x8*)(ap + kk * 32);   // cached dwordx4
                acc0 = __builtin_amdgcn_mfma_f32_16x16x32_bf16(a, bfrag[0][kk], acc0, 0, 0, 0);
                acc1 = __builtin_amdgcn_mfma_f32_16x16x32_bf16(a, bfrag[1][kk], acc1, 0, 0, 0);
            }
        }

        {
            int bat = mi * 16 + fq * 4;
#pragma unroll
            for (int r = 0; r < 4; ++r)
                hz_s[kh][(bat + r) * 28 + fr] = acc0[r];
            if (fr < 8) {
#pragma unroll
                for (int r = 0; r < 4; ++r)
                    hz_s[kh][(bat + r) * 28 + 16 + fr] = acc1[r];
            }
        }
        __syncthreads();

        // gates: one (batch, channel) per thread
        float h0 = hz_s[0][gb * 28 + gi]      + hz_s[1][gb * 28 + gi]      + bh0;
        float h1 = hz_s[0][gb * 28 + 8 + gi]  + hz_s[1][gb * 28 + 8 + gi]  + bh1;
        float h2 = hz_s[0][gb * 28 + 16 + gi] + hz_s[1][gb * 28 + 16 + gi] + bh2;
        float z  = 1.f / (1.f + __expf(-(xg0 + h0)));
        float rr = 1.f / (1.f + __expf(-(xg1 + h1)));
        float pre = xg2 + rr * h2;
        float e2 = __expf(-2.f * pre);
        float nc = (1.f - e2) / (1.f + e2);
        float hold = hold_s[tid];
        float hnew = (1.f - z) * nc + z * hold;
        hold_s[tid] = hnew;
        u16 hv = f2bf(hnew);
        int other = __shfl_xor((int)hv, 1, 64);
        if (!(tid & 1)) {
            u32 packed = (u32)hv | (((u32)(u16)other) << 16);
            __hip_atomic_store((u32*)hsx + (((size_t)n * HSTEP + gb * 768 + gc) >> 1),
                               packed, __ATOMIC_RELAXED, __HIP_MEMORY_SCOPE_AGENT);
        }
        __syncthreads();   // all waves drain vmcnt before arrival
        if (tid == 0)
            __hip_atomic_fetch_add(&cnt[n], 1, __ATOMIC_RELAXED, __HIP_MEMORY_SCOPE_AGENT);
    }
}

// ---------------------------------------------------------------------------
extern "C" void kernel_launch(void* const* d_in, const int* in_sizes, int n_in,
                              void* d_out, int out_size, void* d_ws, size_t ws_size,
                              hipStream_t stream)
{
    const float* x  = (const float*)d_in[0];
    const float* Wx = (const float*)d_in[1];
    const float* bx = (const float*)d_in[2];
    const float* Wh = (const float*)d_in[3];
    const float* bh = (const float*)d_in[4];
    const float* Wp = (const float*)d_in[5];
    float* out = (float*)d_out;

    char* ws = (char*)d_ws;
    size_t off = 0;
    auto wsalloc = [&](size_t bytes) -> void* {
        void* p = ws + off;
        off += (bytes + 255) & ~(size_t)255;
        return p;
    };
    u16* xb   = (u16*)wsalloc(9633792ull * 2);            // x bf16 [12544][768]
    u16* wxb  = (u16*)wsalloc(1769472ull * 2);            // Wx bf16 [2304][768]
    u16* wpb  = (u16*)wsalloc(589824ull * 2);             // Wp bf16 [768][768]
    u16* xzrn = (u16*)wsalloc(196ull * 64 * 2304 * 2);    // [n][b][3C] bf16
    u16* hsx  = (u16*)wsalloc(196ull * 64 * 768 * 2);     // [n][b][C] bf16
    int* cnt  = (int*)wsalloc(1024);

    // 1) converts (+ zero barrier counters)
    cvt_kernel<<<11712, 256, 0, stream>>>(
        (const float4*)x, (const float4*)Wx, (const float4*)Wp,
        (u32*)xb, (u32*)wxb, (u32*)wpb, cnt);

    // 2) x_zrn = seq @ Wx^T + bx  ->  [n][b][3C] bf16
    gemm_bt<1><<<dim3(18, 98), 256, 0, stream>>>(xb, wxb, bx, (void*)xzrn);

    // 3) cooperative recurrence
    {
        const u16* a0 = xzrn; const float* a1 = Wh; const float* a2 = bh;
        u16* a3 = hsx; int* a4 = cnt;
        void* args[5] = { &a0, &a1, &a2, &a3, &a4 };
        hipLaunchCooperativeKernel((void*)recur_kernel, dim3(NWG), dim3(512),
                                   args, 0, stream);
    }

    // 4) y = hsx @ Wp^T -> d_out fp32 (rows m = n*64+b, remapped on store)
    gemm_bt<0><<<dim3(6, 98), 256, 0, stream>>>(hsx, wpb, nullptr, (void*)out);
}

// Round 4
// 1355.200 us; speedup vs baseline: 2.0682x; 1.0975x over previous
//
#include <hip/hip_runtime.h>

typedef unsigned short u16;
typedef unsigned int   u32;
typedef unsigned long long u64;
typedef __attribute__((ext_vector_type(8))) short bf16x8;
typedef __attribute__((ext_vector_type(4))) float f32x4;

#define GK 768            // K dim of all GEMMs
#define NSTEP 196
#define NWG 96            // recurrence workgroups
#define CPW 8             // channels per recurrence wg (96*8 = 768)
#define RROWS 24          // 3 gates * CPW
#define HSTEP 49152       // 64*768 elements per step slab

__device__ __forceinline__ u16 f2bf(float f) {
    u32 u = __float_as_uint(f);
    u = (u + 0x7fffu + ((u >> 16) & 1u)) >> 16;
    return (u16)u;
}
__device__ __forceinline__ float bf2f(u16 h) { return __uint_as_float(((u32)h) << 16); }

// ---------------------------------------------------------------------------
// fp32 -> bf16 convert for x, Wx, Wp; block 0 also zeros the barrier flags
// ---------------------------------------------------------------------------
__global__ __launch_bounds__(256) void cvt_kernel(
    const float4* __restrict__ x, const float4* __restrict__ wx,
    const float4* __restrict__ wp,
    u32* __restrict__ xb, u32* __restrict__ wxb, u32* __restrict__ wpb,
    int* __restrict__ flags)
{
    const int N1 = 9633792 / 4, N2 = 1769472 / 4;
    int i = blockIdx.x * 256 + threadIdx.x;
    if (blockIdx.x == 0) flags[threadIdx.x] = 0;   // 256 >= NWG
    const float4* src; u32* dst; int off;
    if (i < N1)            { src = x;  dst = xb;  off = i; }
    else if (i < N1 + N2)  { src = wx; dst = wxb; off = i - N1; }
    else                   { src = wp; dst = wpb; off = i - N1 - N2; }
    float4 v = src[off];
    u32 lo = (u32)f2bf(v.x) | ((u32)f2bf(v.y) << 16);
    u32 hi = (u32)f2bf(v.z) | ((u32)f2bf(v.w) << 16);
    dst[(size_t)off * 2]     = lo;
    dst[(size_t)off * 2 + 1] = hi;
}

// ---------------------------------------------------------------------------
// GEMM: out[M][N] = A[M][K] @ B[N][K]^T   (A,B bf16 row-major K-contiguous)
// MODE 1: += bias[col], bf16 out remapped to [n][b][col] with m = b*196+n
// MODE 0: fp32 out; A rows are m = n*64+b, output row remapped to b*196+n
// ---------------------------------------------------------------------------
template<int MODE>
__global__ __launch_bounds__(256) void gemm_bt(
    const u16* __restrict__ A, const u16* __restrict__ B,
    const float* __restrict__ bias, void* __restrict__ outv)
{
    __shared__ u16 As[128 * 40];
    __shared__ u16 Bs[128 * 40];
    const int tid  = threadIdx.x;
    const int lane = tid & 63;
    const int wv   = tid >> 6;
    const int m0 = blockIdx.y * 128;
    const int n0 = blockIdx.x * 128;
    const int wm = (wv & 1) * 64;
    const int wn = (wv >> 1) * 64;

    f32x4 acc[4][4];
#pragma unroll
    for (int i = 0; i < 4; ++i)
#pragma unroll
        for (int j = 0; j < 4; ++j) acc[i][j] = (f32x4){0.f, 0.f, 0.f, 0.f};

    const int r0 = tid >> 2, q0 = tid & 3;
    const u16* gA0 = A + (size_t)(m0 + r0)      * GK + q0 * 8;
    const u16* gA1 = A + (size_t)(m0 + r0 + 64) * GK + q0 * 8;
    const u16* gB0 = B + (size_t)(n0 + r0)      * GK + q0 * 8;
    const u16* gB1 = B + (size_t)(n0 + r0 + 64) * GK + q0 * 8;
    u16* sA0 = As + r0 * 40 + q0 * 8;
    u16* sA1 = As + (r0 + 64) * 40 + q0 * 8;
    u16* sB0 = Bs + r0 * 40 + q0 * 8;
    u16* sB1 = Bs + (r0 + 64) * 40 + q0 * 8;

    const int fr = lane & 15, fq = lane >> 4;
    const u16* fA = As + (wm + fr) * 40 + fq * 8;
    const u16* fB = Bs + (wn + fr) * 40 + fq * 8;

    for (int kt = 0; kt < GK / 32; ++kt) {
        uint4 a0 = *(const uint4*)(gA0 + kt * 32);
        uint4 a1 = *(const uint4*)(gA1 + kt * 32);
        uint4 b0 = *(const uint4*)(gB0 + kt * 32);
        uint4 b1 = *(const uint4*)(gB1 + kt * 32);
        __syncthreads();
        *(uint4*)sA0 = a0; *(uint4*)sA1 = a1;
        *(uint4*)sB0 = b0; *(uint4*)sB1 = b1;
        __syncthreads();
        bf16x8 af[4], bfr[4];
#pragma unroll
        for (int mi = 0; mi < 4; ++mi) af[mi]  = *(const bf16x8*)(fA + mi * 16 * 40);
#pragma unroll
        for (int ni = 0; ni < 4; ++ni) bfr[ni] = *(const bf16x8*)(fB + ni * 16 * 40);
#pragma unroll
        for (int mi = 0; mi < 4; ++mi)
#pragma unroll
            for (int ni = 0; ni < 4; ++ni)
                acc[mi][ni] = __builtin_amdgcn_mfma_f32_16x16x32_bf16(
                    af[mi], bfr[ni], acc[mi][ni], 0, 0, 0);
    }

    if (MODE == 1) {
        u16* out = (u16*)outv;
#pragma unroll
        for (int mi = 0; mi < 4; ++mi) {
#pragma unroll
            for (int ni = 0; ni < 4; ++ni) {
                int col = n0 + wn + ni * 16 + fr;
                float bv = bias[col];
#pragma unroll
                for (int r = 0; r < 4; ++r) {
                    int m = m0 + wm + mi * 16 + fq * 4 + r;
                    int b = m / 196;
                    int nn = m - b * 196;
                    u16 hv = f2bf(acc[mi][ni][r] + bv);
                    int other = __shfl_xor((int)hv, 1, 64);
                    if (!(lane & 1)) {
                        u32 packed = (u32)hv | (((u32)(u16)other) << 16);
                        size_t eidx = ((size_t)nn * 64 + (size_t)b) * 2304 + (size_t)col;
                        *((u32*)out + (eidx >> 1)) = packed;
                    }
                }
            }
        }
    } else {
        float* out = (float*)outv;
#pragma unroll
        for (int mi = 0; mi < 4; ++mi) {
#pragma unroll
            for (int ni = 0; ni < 4; ++ni) {
                int col = n0 + wn + ni * 16 + fr;
#pragma unroll
                for (int r = 0; r < 4; ++r) {
                    int m = m0 + wm + mi * 16 + fq * 4 + r;   // m = n*64 + b
                    int b = m & 63;
                    int nn = m >> 6;
                    out[((size_t)b * 196 + nn) * 768 + col] = acc[mi][ni][r];
                }
            }
        }
    }
}

// ---------------------------------------------------------------------------
// Persistent cooperative GRU recurrence.
// 96 wgs x 512 threads (8 waves = 4 batch-tiles x 2 K-halves).
// Wh slice (24 rows) lives in REGISTERS as MFMA B-frags.
// h exchange: rotating slab hsx[n][64][768]; producers publish via 8B
// write-through agent stores; readers use normal cached dwordx4 loads.
// Barrier: per-wg monotonic flag (NO atomic RMW); EVERY wave polls all 96
// flags itself (2 bypass loads/lane + __all), so a wave proceeds the moment
// the last producer's flag lands -- no single-poller release hop.
// ---------------------------------------------------------------------------
__global__ __launch_bounds__(512) void recur_kernel(
    const u16* __restrict__ xz,   // [196][64][2304] bf16 (x proj + bx)
    const float* __restrict__ Wh, // [2304][768] f32
    const float* __restrict__ bh, // [2304] f32
    u16* __restrict__ hsx,        // [196][64][768] bf16 (exchange + output)
    int* flags)                   // [NWG] monotonic step flags (pre-zeroed)
{
    __shared__ float hz_s[2][64 * 28];   // partial h_zrn per K-half, [b][24 pad 28]
    __shared__ float hold_s[512];        // previous h for own channels [b][8]

    const int tid  = threadIdx.x;
    const int wg   = blockIdx.x;
    const int c0   = wg * CPW;
    const int lane = tid & 63;
    const int wv   = tid >> 6;
    const int mi   = wv & 3;     // batch tile (16 batches)
    const int kh   = wv >> 2;    // K half (384 each)
    const int fr   = lane & 15, fq = lane >> 4;

    // one-time: invalidate any stale (poison-era) L1/L2 lines
    __builtin_amdgcn_fence(__ATOMIC_ACQUIRE, "agent");

    // ---- one-time: Wh slice -> B-frags in registers (bf16), rows>=24 zero ----
    bf16x8 bfrag[2][12];
#pragma unroll
    for (int ni = 0; ni < 2; ++ni) {
        int row = ni * 16 + fr;
        bool valid = row < RROWS;
        int gate = row >> 3, ch = row & 7;
        const float* wp = Wh + (size_t)(valid ? (gate * 768 + c0 + ch) : 0) * 768;
#pragma unroll
        for (int kk = 0; kk < 12; ++kk) {
            int k0 = (kh * 12 + kk) * 32 + fq * 8;
            float4 f0 = *(const float4*)(wp + k0);
            float4 f1 = *(const float4*)(wp + k0 + 4);
            bf16x8 b;
            b[0] = (short)f2bf(f0.x); b[1] = (short)f2bf(f0.y);
            b[2] = (short)f2bf(f0.z); b[3] = (short)f2bf(f0.w);
            b[4] = (short)f2bf(f1.x); b[5] = (short)f2bf(f1.y);
            b[6] = (short)f2bf(f1.z); b[7] = (short)f2bf(f1.w);
            if (!valid) b = (bf16x8){0,0,0,0,0,0,0,0};
            bfrag[ni][kk] = b;
        }
    }

    hold_s[tid] = 0.f;
    __syncthreads();

    // gate-phase constants (one (batch,channel) per thread)
    const int gb = tid >> 3, gi = tid & 7;
    const int gc = c0 + gi;
    const float bh0 = bh[gc], bh1 = bh[768 + gc], bh2 = bh[1536 + gc];

    // A-fragment element offset within one step slab
    const int aoff = (mi * 16 + fr) * 768 + kh * 384 + fq * 8;

    for (int n = 0; n < NSTEP; ++n) {
        // prefetch x-projection for this step (independent of h)
        size_t xoff = (size_t)n * 147456 + (size_t)gb * 2304 + (size_t)gc;
        float xg0 = bf2f(xz[xoff]);
        float xg1 = bf2f(xz[xoff + 768]);
        float xg2 = bf2f(xz[xoff + 1536]);

        f32x4 acc0 = (f32x4){0.f, 0.f, 0.f, 0.f};
        f32x4 acc1 = (f32x4){0.f, 0.f, 0.f, 0.f};

        if (n > 0) {
            // every wave polls: all 96 wgs must have published step n-1
            // (flag value n). Lane l checks flags[l] and flags[l+32].
            for (;;) {
                int v0 = __hip_atomic_load(&flags[lane], __ATOMIC_RELAXED,
                                           __HIP_MEMORY_SCOPE_AGENT);
                int v1 = __hip_atomic_load(&flags[lane + 32], __ATOMIC_RELAXED,
                                           __HIP_MEMORY_SCOPE_AGENT);
                if (__all((v0 < v1 ? v0 : v1) >= n)) break;
            }

            const u16* ap = hsx + (size_t)(n - 1) * HSTEP + aoff;
#pragma unroll
            for (int kk = 0; kk < 12; ++kk) {
                bf16x8 a = *(const bf16x8*)(ap + kk * 32);   // cached dwordx4
                acc0 = __builtin_amdgcn_mfma_f32_16x16x32_bf16(a, bfrag[0][kk], acc0, 0, 0, 0);
                acc1 = __builtin_amdgcn_mfma_f32_16x16x32_bf16(a, bfrag[1][kk], acc1, 0, 0, 0);
            }
        }

        {
            int bat = mi * 16 + fq * 4;
#pragma unroll
            for (int r = 0; r < 4; ++r)
                hz_s[kh][(bat + r) * 28 + fr] = acc0[r];
            if (fr < 8) {
#pragma unroll
                for (int r = 0; r < 4; ++r)
                    hz_s[kh][(bat + r) * 28 + 16 + fr] = acc1[r];
            }
        }
        __syncthreads();

        // gates: one (batch, channel) per thread
        float h0 = hz_s[0][gb * 28 + gi]      + hz_s[1][gb * 28 + gi]      + bh0;
        float h1 = hz_s[0][gb * 28 + 8 + gi]  + hz_s[1][gb * 28 + 8 + gi]  + bh1;
        float h2 = hz_s[0][gb * 28 + 16 + gi] + hz_s[1][gb * 28 + 16 + gi] + bh2;
        float z  = 1.f / (1.f + __expf(-(xg0 + h0)));
        float rr = 1.f / (1.f + __expf(-(xg1 + h1)));
        float pre = xg2 + rr * h2;
        float e2 = __expf(-2.f * pre);
        float nc = (1.f - e2) / (1.f + e2);
        float hold = hold_s[tid];
        float hnew = (1.f - z) * nc + z * hold;
        hold_s[tid] = hnew;

        // pack 4 channels -> one 8B write-through store per 4 threads
        u16 hv = f2bf(hnew);
        u32 other = ((u32)__shfl_xor((int)hv, 1, 64)) & 0xffffu;
        u32 v01 = (u32)hv | (other << 16);                  // valid on even gi
        u32 v23 = (u32)__shfl_xor((int)v01, 2, 64);         // pair from gi^2
        if ((tid & 3) == 0) {
            u64 q = (u64)v01 | ((u64)v23 << 32);
            size_t ofs = (size_t)n * HSTEP + (size_t)gb * 768 + (size_t)gc;
            __hip_atomic_store((u64*)((u32*)hsx + (ofs >> 1)), q,
                               __ATOMIC_RELAXED, __HIP_MEMORY_SCOPE_AGENT);
        }
        __syncthreads();   // all waves drain vmcnt before flag publish
        if (tid == 0)
            __hip_atomic_store(&flags[wg], n + 1, __ATOMIC_RELAXED,
                               __HIP_MEMORY_SCOPE_AGENT);
    }
}

// ---------------------------------------------------------------------------
extern "C" void kernel_launch(void* const* d_in, const int* in_sizes, int n_in,
                              void* d_out, int out_size, void* d_ws, size_t ws_size,
                              hipStream_t stream)
{
    const float* x  = (const float*)d_in[0];
    const float* Wx = (const float*)d_in[1];
    const float* bx = (const float*)d_in[2];
    const float* Wh = (const float*)d_in[3];
    const float* bh = (const float*)d_in[4];
    const float* Wp = (const float*)d_in[5];
    float* out = (float*)d_out;

    char* ws = (char*)d_ws;
    size_t off = 0;
    auto wsalloc = [&](size_t bytes) -> void* {
        void* p = ws + off;
        off += (bytes + 255) & ~(size_t)255;
        return p;
    };
    u16* xb   = (u16*)wsalloc(9633792ull * 2);            // x bf16 [12544][768]
    u16* wxb  = (u16*)wsalloc(1769472ull * 2);            // Wx bf16 [2304][768]
    u16* wpb  = (u16*)wsalloc(589824ull * 2);             // Wp bf16 [768][768]
    u16* xzrn = (u16*)wsalloc(196ull * 64 * 2304 * 2);    // [n][b][3C] bf16
    u16* hsx  = (u16*)wsalloc(196ull * 64 * 768 * 2);     // [n][b][C] bf16
    int* flags = (int*)wsalloc(1024);

    // 1) converts (+ zero barrier flags)
    cvt_kernel<<<11712, 256, 0, stream>>>(
        (const float4*)x, (const float4*)Wx, (const float4*)Wp,
        (u32*)xb, (u32*)wxb, (u32*)wpb, flags);

    // 2) x_zrn = seq @ Wx^T + bx  ->  [n][b][3C] bf16
    gemm_bt<1><<<dim3(18, 98), 256, 0, stream>>>(xb, wxb, bx, (void*)xzrn);

    // 3) cooperative recurrence
    {
        const u16* a0 = xzrn; const float* a1 = Wh; const float* a2 = bh;
        u16* a3 = hsx; int* a4 = flags;
        void* args[5] = { &a0, &a1, &a2, &a3, &a4 };
        hipLaunchCooperativeKernel((void*)recur_kernel, dim3(NWG), dim3(512),
                                   args, 0, stream);
    }

    // 4) y = hsx @ Wp^T -> d_out fp32 (rows m = n*64+b, remapped on store)
    gemm_bt<0><<<dim3(6, 98), 256, 0, stream>>>(hsx, wpb, nullptr, (void*)out);
}